// Round 1
// baseline (2136.637 us; speedup 1.0000x reference)
//
#include <hip/hip_runtime.h>
#include <math.h>

// Problem constants (from reference): B=2, S=2048, D=1024, F=4096, H=16, hd=64
#define BB 2
#define SS 2048
#define DD 1024
#define FF 4096
#define HH 16
#define HD 64
#define MM (BB * SS)   // 4096 rows

__device__ __forceinline__ float gelu_tanh(float x) {
    // jax.nn.gelu(approximate=True): 0.5x(1+tanh(sqrt(2/pi)(x+0.044715x^3)))
    float x3 = x * x * x;
    return 0.5f * x * (1.0f + tanhf(0.7978845608028654f * (x + 0.044715f * x3)));
}

// ---------------------------------------------------------------------------
// srmsnorm: out[row] = x[row] / max(||x[row]||, 1e-12) * sqrt(D)
// one block per row, 256 threads, float4 per thread (D=1024)
// ---------------------------------------------------------------------------
__global__ __launch_bounds__(256) void srmsnorm_k(const float* __restrict__ in,
                                                  float* __restrict__ out) {
    const int row = blockIdx.x;
    const int t = threadIdx.x;
    float4 a = reinterpret_cast<const float4*>(in + (size_t)row * DD)[t];
    float ss = a.x * a.x + a.y * a.y + a.z * a.z + a.w * a.w;
#pragma unroll
    for (int off = 32; off > 0; off >>= 1) ss += __shfl_xor(ss, off);
    __shared__ float red[4];
    if ((t & 63) == 0) red[t >> 6] = ss;
    __syncthreads();
    float tot = red[0] + red[1] + red[2] + red[3];
    float scale = 32.0f / fmaxf(sqrtf(tot), 1e-12f);   // sqrt(1024) = 32
    float4 o;
    o.x = a.x * scale; o.y = a.y * scale; o.z = a.z * scale; o.w = a.w * scale;
    reinterpret_cast<float4*>(out + (size_t)row * DD)[t] = o;
}

// ---------------------------------------------------------------------------
// fp32 GEMM: C[M,N] = A[M,K] @ B[K,N]  (+ epilogue)
// EPI 0: none   EPI 1: C = Res + A@B   EPI 2: C = gelu(A@B)
// 64x64 block tile, BK=16, 256 threads, 4x4 per thread.
// A staged transposed (As[k][m]) so both LDS operands read as float4.
// ---------------------------------------------------------------------------
template <int EPI>
__global__ __launch_bounds__(256) void gemm_f32(const float* __restrict__ A,
                                                const float* __restrict__ Bw,
                                                const float* __restrict__ Res,
                                                float* __restrict__ C,
                                                int M, int N, int K) {
    __shared__ float As[16][68];   // [k][m], pad 68: 2-way max on reads
    __shared__ float Bs[16][68];   // [k][n]
    const int t = threadIdx.x;
    const int tx = t & 15, ty = t >> 4;        // tx -> N, ty -> M
    const int bm = blockIdx.y * 64, bn = blockIdx.x * 64;
    const int ar = t >> 2, ak = (t & 3) * 4;   // A tile: row ar, k-offset ak
    const int bkr = t >> 4, bc = (t & 15) * 4; // B tile: k-row bkr, col bc

    float acc[4][4] = {{0.0f}};
    for (int k0 = 0; k0 < K; k0 += 16) {
        float4 a4 = *reinterpret_cast<const float4*>(&A[(size_t)(bm + ar) * K + k0 + ak]);
        float4 b4 = *reinterpret_cast<const float4*>(&Bw[(size_t)(k0 + bkr) * N + bn + bc]);
        __syncthreads();   // previous iteration's reads complete
        As[ak + 0][ar] = a4.x; As[ak + 1][ar] = a4.y;
        As[ak + 2][ar] = a4.z; As[ak + 3][ar] = a4.w;
        *reinterpret_cast<float4*>(&Bs[bkr][bc]) = b4;
        __syncthreads();
#pragma unroll
        for (int kk = 0; kk < 16; ++kk) {
            float4 av = *reinterpret_cast<const float4*>(&As[kk][ty * 4]);
            float4 bv = *reinterpret_cast<const float4*>(&Bs[kk][tx * 4]);
            float aa[4] = {av.x, av.y, av.z, av.w};
            float bb[4] = {bv.x, bv.y, bv.z, bv.w};
#pragma unroll
            for (int i = 0; i < 4; ++i)
#pragma unroll
                for (int j = 0; j < 4; ++j)
                    acc[i][j] = fmaf(aa[i], bb[j], acc[i][j]);
        }
    }
#pragma unroll
    for (int i = 0; i < 4; ++i) {
        size_t off = (size_t)(bm + ty * 4 + i) * N + bn + tx * 4;
        float4 r;
        r.x = acc[i][0]; r.y = acc[i][1]; r.z = acc[i][2]; r.w = acc[i][3];
        if (EPI == 1) {
            float4 res = *reinterpret_cast<const float4*>(&Res[off]);
            r.x += res.x; r.y += res.y; r.z += res.z; r.w += res.w;
        } else if (EPI == 2) {
            r.x = gelu_tanh(r.x); r.y = gelu_tanh(r.y);
            r.z = gelu_tanh(r.z); r.w = gelu_tanh(r.w);
        }
        *reinterpret_cast<float4*>(&C[off]) = r;
    }
}

// ---------------------------------------------------------------------------
// Causal flash attention, fp32. Layout of q/k/v/o: [B, S, H*hd] (row-major,
// head h occupies cols h*64..h*64+63). One block = one (b,h) x 64-row q-tile.
// 256 threads: thread (ty,tx) owns score/O subtile rows ty*4.., cols tx*4..
// P tile is written back into the K LDS buffer (K dead after scores).
// LDS: 3 * 64*68*4 = 51 KB.
// ---------------------------------------------------------------------------
__global__ __launch_bounds__(256) void attn_k(const float* __restrict__ Q,
                                              const float* __restrict__ K,
                                              const float* __restrict__ V,
                                              float* __restrict__ O) {
    __shared__ float Qs[64][68];
    __shared__ float KPs[64][68];   // K tile, then P tile
    __shared__ float Vs[64][68];
    const int t = threadIdx.x;
    const int tx = t & 15, ty = t >> 4;
    const int rb = ty * 4, cb = tx * 4;
    const int qt = blockIdx.x, bh = blockIdx.y;
    const int b = bh / HH, h = bh % HH;
    const size_t base = (size_t)b * SS * DD + (size_t)h * HD;

    // load Q tile (64 rows x 64 cols)
#pragma unroll
    for (int it = 0; it < 4; ++it) {
        int id = it * 256 + t;
        int r = id >> 4, c = (id & 15) * 4;
        *reinterpret_cast<float4*>(&Qs[r][c]) =
            *reinterpret_cast<const float4*>(&Q[base + (size_t)(qt * 64 + r) * DD + c]);
    }

    float o[4][4] = {{0.0f}};
    float m_run[4] = {-1e30f, -1e30f, -1e30f, -1e30f};
    float l_run[4] = {0.0f, 0.0f, 0.0f, 0.0f};

    for (int kt = 0; kt <= qt; ++kt) {
        __syncthreads();   // previous tile's LDS reads complete
#pragma unroll
        for (int it = 0; it < 4; ++it) {
            int id = it * 256 + t;
            int r = id >> 4, c = (id & 15) * 4;
            size_t g = base + (size_t)(kt * 64 + r) * DD + c;
            *reinterpret_cast<float4*>(&KPs[r][c]) = *reinterpret_cast<const float4*>(&K[g]);
            *reinterpret_cast<float4*>(&Vs[r][c])  = *reinterpret_cast<const float4*>(&V[g]);
        }
        __syncthreads();

        // scores s = Q K^T (4x4 subtile per thread)
        float s[4][4] = {{0.0f}};
        for (int d0 = 0; d0 < 64; d0 += 4) {
            float4 q4[4], k4[4];
#pragma unroll
            for (int i = 0; i < 4; ++i)
                q4[i] = *reinterpret_cast<const float4*>(&Qs[rb + i][d0]);
#pragma unroll
            for (int j = 0; j < 4; ++j)
                k4[j] = *reinterpret_cast<const float4*>(&KPs[cb + j][d0]);
#pragma unroll
            for (int i = 0; i < 4; ++i)
#pragma unroll
                for (int j = 0; j < 4; ++j)
                    s[i][j] += q4[i].x * k4[j].x + q4[i].y * k4[j].y +
                               q4[i].z * k4[j].z + q4[i].w * k4[j].w;
        }
        // scale + causal mask (only diagonal tile has masked entries)
        const bool diag = (kt == qt);
#pragma unroll
        for (int i = 0; i < 4; ++i)
#pragma unroll
            for (int j = 0; j < 4; ++j) {
                bool ok = !diag || (cb + j <= rb + i);
                s[i][j] = ok ? s[i][j] * 0.125f : -1e30f;   // hd^-0.5 = 1/8
            }

        // online softmax: rows shared by 16 consecutive lanes (same ty)
        float corr[4];
#pragma unroll
        for (int i = 0; i < 4; ++i) {
            float m0 = fmaxf(fmaxf(s[i][0], s[i][1]), fmaxf(s[i][2], s[i][3]));
            m0 = fmaxf(m0, __shfl_xor(m0, 1));
            m0 = fmaxf(m0, __shfl_xor(m0, 2));
            m0 = fmaxf(m0, __shfl_xor(m0, 4));
            m0 = fmaxf(m0, __shfl_xor(m0, 8));
            float mn = fmaxf(m_run[i], m0);
            float p0 = expf(s[i][0] - mn), p1 = expf(s[i][1] - mn);
            float p2 = expf(s[i][2] - mn), p3 = expf(s[i][3] - mn);
            float ts = p0 + p1 + p2 + p3;
            ts += __shfl_xor(ts, 1); ts += __shfl_xor(ts, 2);
            ts += __shfl_xor(ts, 4); ts += __shfl_xor(ts, 8);
            float c_ = expf(m_run[i] - mn);
            l_run[i] = l_run[i] * c_ + ts;
            m_run[i] = mn;
            corr[i] = c_;
            s[i][0] = p0; s[i][1] = p1; s[i][2] = p2; s[i][3] = p3;
        }

        __syncthreads();   // everyone done reading K before P overwrites it
#pragma unroll
        for (int i = 0; i < 4; ++i) {
            float4 pv;
            pv.x = s[i][0]; pv.y = s[i][1]; pv.z = s[i][2]; pv.w = s[i][3];
            *reinterpret_cast<float4*>(&KPs[rb + i][cb]) = pv;
            o[i][0] *= corr[i]; o[i][1] *= corr[i];
            o[i][2] *= corr[i]; o[i][3] *= corr[i];
        }
        // P rows rb..rb+3 are written and read by the same 16-lane group
        // (same wave) -> in-order DS, no barrier needed.

        // O += P @ V  (thread owns rows rb.., output dims cb..)
#pragma unroll
        for (int c0 = 0; c0 < 64; c0 += 4) {
            float pr[4][4];
#pragma unroll
            for (int i = 0; i < 4; ++i) {
                float4 t4 = *reinterpret_cast<const float4*>(&KPs[rb + i][c0]);
                pr[i][0] = t4.x; pr[i][1] = t4.y; pr[i][2] = t4.z; pr[i][3] = t4.w;
            }
#pragma unroll
            for (int cc = 0; cc < 4; ++cc) {
                float4 v4 = *reinterpret_cast<const float4*>(&Vs[c0 + cc][cb]);
#pragma unroll
                for (int i = 0; i < 4; ++i) {
                    o[i][0] += pr[i][cc] * v4.x; o[i][1] += pr[i][cc] * v4.y;
                    o[i][2] += pr[i][cc] * v4.z; o[i][3] += pr[i][cc] * v4.w;
                }
            }
        }
    }

    // epilogue: O / l
#pragma unroll
    for (int i = 0; i < 4; ++i) {
        float inv = 1.0f / l_run[i];
        float4 ov;
        ov.x = o[i][0] * inv; ov.y = o[i][1] * inv;
        ov.z = o[i][2] * inv; ov.w = o[i][3] * inv;
        *reinterpret_cast<float4*>(&O[base + (size_t)(qt * 64 + rb + i) * DD + cb]) = ov;
    }
}

// ---------------------------------------------------------------------------
// launch: h = x + attn(srmsnorm(x)); out = h + gelu(srmsnorm(h)@w_in)@w_out
// Workspace layout (floats), SZ = 4096*1024:
//   [0,SZ)      xn  (later reused as attention output)
//   [SZ,2SZ)    q   [2SZ,3SZ) k   [3SZ,4SZ) v
//   [4SZ,5SZ)   hn
//   [5SZ,9SZ)   g = gelu(hn@w_in)   (MM x FF)
// total 9*SZ*4B = 144 MB of d_ws. h lives in d_out.
// ---------------------------------------------------------------------------
extern "C" void kernel_launch(void* const* d_in, const int* in_sizes, int n_in,
                              void* d_out, int out_size, void* d_ws, size_t ws_size,
                              hipStream_t stream) {
    const float* x     = (const float*)d_in[0];
    const float* wq    = (const float*)d_in[1];
    const float* wk    = (const float*)d_in[2];
    const float* wv    = (const float*)d_in[3];
    const float* wo    = (const float*)d_in[4];
    const float* w_in  = (const float*)d_in[5];
    const float* w_out = (const float*)d_in[6];
    float* out = (float*)d_out;
    float* ws  = (float*)d_ws;

    const size_t SZ = (size_t)MM * DD;
    float* xn = ws;            // -> reused as attention output
    float* q  = ws + SZ;
    float* k  = ws + 2 * SZ;
    float* v  = ws + 3 * SZ;
    float* hn = ws + 4 * SZ;
    float* g  = ws + 5 * SZ;   // MM x FF

    dim3 blk(256);
    dim3 gdd(DD / 64, MM / 64);

    srmsnorm_k<<<MM, blk, 0, stream>>>(x, xn);
    gemm_f32<0><<<gdd, blk, 0, stream>>>(xn, wq, nullptr, q, MM, DD, DD);
    gemm_f32<0><<<gdd, blk, 0, stream>>>(xn, wk, nullptr, k, MM, DD, DD);
    gemm_f32<0><<<gdd, blk, 0, stream>>>(xn, wv, nullptr, v, MM, DD, DD);
    attn_k<<<dim3(SS / 64, BB * HH), blk, 0, stream>>>(q, k, v, xn);
    gemm_f32<1><<<gdd, blk, 0, stream>>>(xn, wo, x, out, MM, DD, DD);      // h
    srmsnorm_k<<<MM, blk, 0, stream>>>(out, hn);
    gemm_f32<2><<<dim3(FF / 64, MM / 64), blk, 0, stream>>>(hn, w_in, nullptr, g, MM, FF, DD);
    gemm_f32<1><<<gdd, blk, 0, stream>>>(g, w_out, out, out, MM, DD, FF);  // out = h + ff
}

// Round 4
// 459.446 us; speedup vs baseline: 4.6505x; 4.6505x over previous
//
#include <hip/hip_runtime.h>
#include <math.h>

// B=2, S=2048, D=1024, F=4096, H=16, hd=64
#define BB 2
#define SS 2048
#define DD 1024
#define FF 4096
#define HH 16
#define MM (BB * SS)  // 4096

typedef __attribute__((ext_vector_type(8))) short short8v;
typedef __attribute__((ext_vector_type(4))) float float4v;
typedef __attribute__((ext_vector_type(4))) unsigned short ushort4v;
typedef __attribute__((ext_vector_type(8))) unsigned short ushort8v;
typedef unsigned short u16;
typedef unsigned int u32;

#define MFMA16(A_, B_, C_) __builtin_amdgcn_mfma_f32_16x16x32_bf16((A_), (B_), (C_), 0, 0, 0)

__device__ __forceinline__ u16 f2bf(float f) {  // RNE float->bf16
    u32 u = __float_as_uint(f);
    u += 0x7FFF + ((u >> 16) & 1);
    return (u16)(u >> 16);
}

__device__ __forceinline__ void async16(void* lds, const void* g) {
    __builtin_amdgcn_global_load_lds(
        (const __attribute__((address_space(1))) u32*)g,
        (__attribute__((address_space(3))) u32*)lds, 16, 0, 0);
}

__device__ __forceinline__ float gelu_f(float x) {
    // 0.5x(1+tanh(0.79788456(x+0.044715x^3))), tanh via exp2
    float u = 0.7978845608028654f * x * (1.0f + 0.044715f * x * x);
    float e = exp2f(u * 2.8853900817779268f);   // e^{2u}
    float th = 1.0f - 2.0f / (e + 1.0f);
    return 0.5f * x * (1.0f + th);
}

// ---------------------------------------------------------------------------
// srmsnorm: f32 in -> bf16 out. One block per row, 256 thr, float4/thread.
// ---------------------------------------------------------------------------
__global__ __launch_bounds__(256) void srmsnorm_bf16(const float* __restrict__ in,
                                                     u16* __restrict__ out) {
    const int row = blockIdx.x, t = threadIdx.x;
    float4 a = reinterpret_cast<const float4*>(in + (size_t)row * DD)[t];
    float ss = a.x * a.x + a.y * a.y + a.z * a.z + a.w * a.w;
#pragma unroll
    for (int off = 32; off > 0; off >>= 1) ss += __shfl_xor(ss, off);
    __shared__ float red[4];
    if ((t & 63) == 0) red[t >> 6] = ss;
    __syncthreads();
    float tot = red[0] + red[1] + red[2] + red[3];
    float sc = 32.0f / fmaxf(sqrtf(tot), 1e-12f);   // sqrt(1024)=32
    ushort4v ov;
    ov[0] = f2bf(a.x * sc); ov[1] = f2bf(a.y * sc);
    ov[2] = f2bf(a.z * sc); ov[3] = f2bf(a.w * sc);
    *(ushort4v*)(out + (size_t)row * DD + t * 4) = ov;
}

// ---------------------------------------------------------------------------
// weight transpose+cast: in f32 [K][N] -> out bf16 [N][K]. 64x64 tiles.
// ---------------------------------------------------------------------------
__global__ __launch_bounds__(256) void wtrans(const float* __restrict__ in,
                                              u16* __restrict__ out, int K, int N) {
    __shared__ float T[64][65];
    const int t = threadIdx.x;
    const int n0 = blockIdx.x * 64, k0 = blockIdx.y * 64;
#pragma unroll
    for (int i = 0; i < 4; ++i) {
        int r = i * 16 + (t >> 4), c4 = (t & 15) * 4;
        float4 v = *reinterpret_cast<const float4*>(in + (size_t)(k0 + r) * N + n0 + c4);
        T[r][c4 + 0] = v.x; T[r][c4 + 1] = v.y; T[r][c4 + 2] = v.z; T[r][c4 + 3] = v.w;
    }
    __syncthreads();
#pragma unroll
    for (int i = 0; i < 4; ++i) {
        int r = i * 16 + (t >> 4), c4 = (t & 15) * 4;
        ushort4v ov;
#pragma unroll
        for (int j = 0; j < 4; ++j) ov[j] = f2bf(T[c4 + j][r]);
        *(ushort4v*)(out + (size_t)(n0 + r) * K + k0 + c4) = ov;
    }
}

// ---------------------------------------------------------------------------
// V transpose: vb bf16 [B*S][D] -> vt bf16 [B*H][64][S]
// pad 88 (stride 176B): keeps 16B stores aligned (144B stride at pad 72 was
// a misaligned-b128 bug).
// ---------------------------------------------------------------------------
__global__ __launch_bounds__(256) void vtrans(const u16* __restrict__ vb,
                                              u16* __restrict__ vt) {
    __shared__ u16 T[64][88];
    const int t = threadIdx.x;
    const int s0 = blockIdx.x * 64, bh = blockIdx.y;
    const int b = bh >> 4, h = bh & 15;
#pragma unroll
    for (int i = 0; i < 2; ++i) {
        int r = i * 32 + (t >> 3), c8 = (t & 7) * 8;
        *(ushort8v*)&T[r][c8] =
            *(const ushort8v*)(vb + (size_t)(b * SS + s0 + r) * DD + h * 64 + c8);
    }
    __syncthreads();
#pragma unroll
    for (int i = 0; i < 2; ++i) {
        int d = i * 32 + (t >> 3), s8 = (t & 7) * 8;
        ushort8v ov;
#pragma unroll
        for (int j = 0; j < 8; ++j) ov[j] = T[s8 + j][d];
        *(ushort8v*)(vt + ((size_t)bh * 64 + d) * SS + s0 + s8) = ov;
    }
}

// ---------------------------------------------------------------------------
// bf16 MFMA GEMM (m97 structure): C[M,N] = A[M,K] * Bt[N,K]^T
// BK=32, 256 thr = 4 waves (2x2), global_load_lds width 16, 2 barriers/K-step.
// EPI 0: bf16 out. EPI 1: f32 out = acc + Res. EPI 2: bf16 out = gelu(acc).
// ---------------------------------------------------------------------------
template <int BM, int BN, int EPI>
__global__ __launch_bounds__(256) void gemm_bf16(const u16* __restrict__ A,
                                                 const u16* __restrict__ Bt,
                                                 const float* __restrict__ Res,
                                                 void* __restrict__ Cout,
                                                 int M, int N, int K) {
    __shared__ u16 As[BM * 32];
    __shared__ u16 Bs[BN * 32];
    constexpr int FM = BM / 32, FN = BN / 32;
    const int t = threadIdx.x;
    const int w = t >> 6, lane = t & 63;
    const int g = lane >> 4, c = lane & 15;
    const int wr = w >> 1, wc = w & 1;
    const int bm = blockIdx.y * BM, bn = blockIdx.x * BN;
    const int arow = t >> 2, au = (t & 3) * 8;   // staging: 16B per thread

    float4v acc[FM][FN] = {};
    for (int k0 = 0; k0 < K; k0 += 32) {
        __syncthreads();   // prev iteration's LDS reads done
#pragma unroll
        for (int p = 0; p < BM / 64; ++p)
            async16(&As[(p * 64 + arow) * 32 + au],
                    A + (size_t)(bm + p * 64 + arow) * K + k0 + au);
#pragma unroll
        for (int p = 0; p < BN / 64; ++p)
            async16(&Bs[(p * 64 + arow) * 32 + au],
                    Bt + (size_t)(bn + p * 64 + arow) * K + k0 + au);
        __syncthreads();   // drains vmcnt -> LDS visible
        short8v af[FM], bf[FN];
#pragma unroll
        for (int mi = 0; mi < FM; ++mi)
            af[mi] = *(const short8v*)&As[(wr * (BM / 2) + mi * 16 + c) * 32 + g * 8];
#pragma unroll
        for (int ni = 0; ni < FN; ++ni)
            bf[ni] = *(const short8v*)&Bs[(wc * (BN / 2) + ni * 16 + c) * 32 + g * 8];
#pragma unroll
        for (int mi = 0; mi < FM; ++mi)
#pragma unroll
            for (int ni = 0; ni < FN; ++ni)
                acc[mi][ni] = MFMA16(af[mi], bf[ni], acc[mi][ni]);
    }
    const int row0 = bm + wr * (BM / 2), col0 = bn + wc * (BN / 2);
#pragma unroll
    for (int mi = 0; mi < FM; ++mi)
#pragma unroll
        for (int r = 0; r < 4; ++r) {
            const size_t rw = (size_t)(row0 + mi * 16 + 4 * g + r) * N;
#pragma unroll
            for (int ni = 0; ni < FN; ++ni) {
                const size_t off = rw + col0 + ni * 16 + c;
                float v = acc[mi][ni][r];
                if (EPI == 0)      ((u16*)Cout)[off] = f2bf(v);
                else if (EPI == 1) ((float*)Cout)[off] = v + Res[off];
                else               ((u16*)Cout)[off] = f2bf(gelu_f(v));
            }
        }
}

// ---------------------------------------------------------------------------
// Causal flash attention, bf16 MFMA. qb,kb: [B*S][D] bf16; vt: [B*H][64][S].
// 4 independent waves/block, 32 q-rows each; K/V fragments straight from
// global (L2-resident); P lane-transpose via padded LDS (pad 88: 16B-aligned
// rows + 2-way-only bank aliasing). LPT: heavy qt first.
// ---------------------------------------------------------------------------
__global__ __launch_bounds__(256) void attn_mfma(const u16* __restrict__ Qb,
                                                 const u16* __restrict__ Kb,
                                                 const u16* __restrict__ Vt,
                                                 u16* __restrict__ Ao) {
    __shared__ u16 Pl[4][2][16][88];
    const int t = threadIdx.x;
    const int w = t >> 6, lane = t & 63;
    const int g = lane >> 4, c = lane & 15;
    const int bh = blockIdx.x;
    const int qt = (int)(gridDim.y - 1) - (int)blockIdx.y;  // heavy first
    const int b = bh >> 4, h = bh & 15;
    const int qrow0 = qt * 128 + w * 32;
    const int ktmax = (qrow0 + 31) >> 6;
    const size_t qkbase = (size_t)b * SS * DD + h * 64;
    const size_t vbase = (size_t)bh * 64 * SS;
    constexpr float SC = 0.18033688011112042f;  // 0.125 * log2(e)

    short8v qf[2][2];
#pragma unroll
    for (int rb = 0; rb < 2; ++rb)
#pragma unroll
        for (int kh = 0; kh < 2; ++kh)
            qf[rb][kh] = *(const short8v*)(Qb + qkbase +
                             (size_t)(qrow0 + rb * 16 + c) * DD + kh * 32 + g * 8);

    float4v o[2][4] = {};
    float m_run[2][4], l_run[2][4];
#pragma unroll
    for (int rb = 0; rb < 2; ++rb)
#pragma unroll
        for (int r = 0; r < 4; ++r) { m_run[rb][r] = -1e30f; l_run[rb][r] = 0.0f; }

    for (int kt = 0; kt <= ktmax; ++kt) {
        // ---- scores S = Q K^T ----
        short8v kf[4][2];
#pragma unroll
        for (int nb = 0; nb < 4; ++nb)
#pragma unroll
            for (int kh = 0; kh < 2; ++kh)
                kf[nb][kh] = *(const short8v*)(Kb + qkbase +
                                 (size_t)(kt * 64 + nb * 16 + c) * DD + kh * 32 + g * 8);
        float4v sa[2][4] = {};
#pragma unroll
        for (int nb = 0; nb < 4; ++nb)
#pragma unroll
            for (int kh = 0; kh < 2; ++kh)
#pragma unroll
                for (int rb = 0; rb < 2; ++rb)
                    sa[rb][nb] = MFMA16(qf[rb][kh], kf[nb][kh], sa[rb][nb]);

        const bool diag = (kt == ktmax);
#pragma unroll
        for (int rb = 0; rb < 2; ++rb)
#pragma unroll
            for (int nb = 0; nb < 4; ++nb)
#pragma unroll
                for (int r = 0; r < 4; ++r) {
                    float v = sa[rb][nb][r] * SC;
                    if (diag && (kt * 64 + nb * 16 + c > qrow0 + rb * 16 + 4 * g + r))
                        v = -3e38f;
                    sa[rb][nb][r] = v;
                }

        // ---- online softmax (rows live in 16-lane groups) ----
#pragma unroll
        for (int rb = 0; rb < 2; ++rb) {
            float mx[4], corr[4];
#pragma unroll
            for (int r = 0; r < 4; ++r) {
                float m0 = fmaxf(fmaxf(sa[rb][0][r], sa[rb][1][r]),
                                 fmaxf(sa[rb][2][r], sa[rb][3][r]));
                m0 = fmaxf(m0, __shfl_xor(m0, 1));
                m0 = fmaxf(m0, __shfl_xor(m0, 2));
                m0 = fmaxf(m0, __shfl_xor(m0, 4));
                m0 = fmaxf(m0, __shfl_xor(m0, 8));
                float mn = fmaxf(m_run[rb][r], m0);
                corr[r] = exp2f(m_run[rb][r] - mn);
                m_run[rb][r] = mn;
                mx[r] = mn;
            }
#pragma unroll
            for (int nb = 0; nb < 4; ++nb)
#pragma unroll
                for (int r = 0; r < 4; ++r)
                    sa[rb][nb][r] = exp2f(sa[rb][nb][r] - mx[r]);
#pragma unroll
            for (int r = 0; r < 4; ++r) {
                float s_ = sa[rb][0][r] + sa[rb][1][r] + sa[rb][2][r] + sa[rb][3][r];
                s_ += __shfl_xor(s_, 1); s_ += __shfl_xor(s_, 2);
                s_ += __shfl_xor(s_, 4); s_ += __shfl_xor(s_, 8);
                l_run[rb][r] = l_run[rb][r] * corr[r] + s_;
            }
            float4v cv; cv[0] = corr[0]; cv[1] = corr[1]; cv[2] = corr[2]; cv[3] = corr[3];
#pragma unroll
            for (int nb = 0; nb < 4; ++nb) o[rb][nb] *= cv;
            // P -> bf16 -> LDS (lane transpose for A-fragment)
#pragma unroll
            for (int nb = 0; nb < 4; ++nb)
#pragma unroll
                for (int r = 0; r < 4; ++r)
                    Pl[w][rb][4 * g + r][nb * 16 + c] = f2bf(sa[rb][nb][r]);
        }

        // ---- O += P V ----
        short8v pa[2][2];
#pragma unroll
        for (int rb = 0; rb < 2; ++rb)
#pragma unroll
            for (int kh = 0; kh < 2; ++kh)
                pa[rb][kh] = *(const short8v*)&Pl[w][rb][c][kh * 32 + g * 8];
        short8v vf[4][2];
#pragma unroll
        for (int nb = 0; nb < 4; ++nb)
#pragma unroll
            for (int kh = 0; kh < 2; ++kh)
                vf[nb][kh] = *(const short8v*)(Vt + vbase +
                                 (size_t)(nb * 16 + c) * SS + kt * 64 + kh * 32 + g * 8);
#pragma unroll
        for (int nb = 0; nb < 4; ++nb)
#pragma unroll
            for (int kh = 0; kh < 2; ++kh)
#pragma unroll
                for (int rb = 0; rb < 2; ++rb)
                    o[rb][nb] = MFMA16(pa[rb][kh], vf[nb][kh], o[rb][nb]);
    }

    // epilogue: O / l -> bf16
#pragma unroll
    for (int rb = 0; rb < 2; ++rb) {
        float inv[4];
#pragma unroll
        for (int r = 0; r < 4; ++r) inv[r] = 1.0f / l_run[rb][r];
#pragma unroll
        for (int nb = 0; nb < 4; ++nb)
#pragma unroll
            for (int r = 0; r < 4; ++r)
                Ao[qkbase + (size_t)(qrow0 + rb * 16 + 4 * g + r) * DD + nb * 16 + c] =
                    f2bf(o[rb][nb][r] * inv[r]);
    }
}

// ---------------------------------------------------------------------------
// launch: h = x + attn(srmsnorm(x)); out = h + gelu(srmsnorm(h)@w_in)@w_out
// ws layout (MB): 0 wq_t | 2 wk_t | 4 wv_t | 6 wo_t | 8 wi_t | 16 wo2_t |
//  24 xn | 32 qb | 40 kb | 48 vb | 56 vt | 64 ao | 72 hn | 80 g(32MB) = 112MB
// ---------------------------------------------------------------------------
extern "C" void kernel_launch(void* const* d_in, const int* in_sizes, int n_in,
                              void* d_out, int out_size, void* d_ws, size_t ws_size,
                              hipStream_t stream) {
    const float* x     = (const float*)d_in[0];
    const float* wq    = (const float*)d_in[1];
    const float* wk    = (const float*)d_in[2];
    const float* wv    = (const float*)d_in[3];
    const float* wo    = (const float*)d_in[4];
    const float* w_in  = (const float*)d_in[5];
    const float* w_out = (const float*)d_in[6];
    float* out = (float*)d_out;
    char* ws = (char*)d_ws;
    const size_t MB = 1024 * 1024;
    u16* wq_t  = (u16*)(ws + 0 * MB);
    u16* wk_t  = (u16*)(ws + 2 * MB);
    u16* wv_t  = (u16*)(ws + 4 * MB);
    u16* wo_t  = (u16*)(ws + 6 * MB);
    u16* wi_t  = (u16*)(ws + 8 * MB);
    u16* wo2_t = (u16*)(ws + 16 * MB);
    u16* xn    = (u16*)(ws + 24 * MB);
    u16* qb    = (u16*)(ws + 32 * MB);
    u16* kb    = (u16*)(ws + 40 * MB);
    u16* vb    = (u16*)(ws + 48 * MB);
    u16* vt    = (u16*)(ws + 56 * MB);
    u16* ao    = (u16*)(ws + 64 * MB);
    u16* hn    = (u16*)(ws + 72 * MB);
    u16* gbuf  = (u16*)(ws + 80 * MB);

    dim3 blk(256);
    // weights -> bf16 transposed [N][K]
    wtrans<<<dim3(DD / 64, DD / 64), blk, 0, stream>>>(wq, wq_t, DD, DD);
    wtrans<<<dim3(DD / 64, DD / 64), blk, 0, stream>>>(wk, wk_t, DD, DD);
    wtrans<<<dim3(DD / 64, DD / 64), blk, 0, stream>>>(wv, wv_t, DD, DD);
    wtrans<<<dim3(DD / 64, DD / 64), blk, 0, stream>>>(wo, wo_t, DD, DD);
    wtrans<<<dim3(FF / 64, DD / 64), blk, 0, stream>>>(w_in, wi_t, DD, FF);
    wtrans<<<dim3(DD / 64, FF / 64), blk, 0, stream>>>(w_out, wo2_t, FF, DD);

    srmsnorm_bf16<<<MM, blk, 0, stream>>>(x, xn);
    gemm_bf16<128, 64, 0><<<dim3(DD / 64, MM / 128), blk, 0, stream>>>(xn, wq_t, nullptr, qb, MM, DD, DD);
    gemm_bf16<128, 64, 0><<<dim3(DD / 64, MM / 128), blk, 0, stream>>>(xn, wk_t, nullptr, kb, MM, DD, DD);
    gemm_bf16<128, 64, 0><<<dim3(DD / 64, MM / 128), blk, 0, stream>>>(xn, wv_t, nullptr, vb, MM, DD, DD);
    vtrans<<<dim3(SS / 64, BB * HH), blk, 0, stream>>>(vb, vt);
    attn_mfma<<<dim3(BB * HH, SS / 128), blk, 0, stream>>>(qb, kb, vt, ao);
    gemm_bf16<128, 64, 1><<<dim3(DD / 64, MM / 128), blk, 0, stream>>>(ao, wo_t, x, out, MM, DD, DD);   // h
    srmsnorm_bf16<<<MM, blk, 0, stream>>>(out, hn);
    gemm_bf16<128, 128, 2><<<dim3(FF / 128, MM / 128), blk, 0, stream>>>(hn, wi_t, nullptr, gbuf, MM, FF, DD);
    gemm_bf16<128, 64, 1><<<dim3(DD / 64, MM / 128), blk, 0, stream>>>(gbuf, wo2_t, out, out, MM, DD, FF); // h+ff
}